// Round 5
// baseline (22099.191 us; speedup 1.0000x reference)
//
#include <hip/hip_runtime.h>
#include <hip/hip_bf16.h>

// EnsembleRSSM observe scan: B=256, T=64, STOCH=32, DETER=1024, HIDDEN=1024,
// EMBED=1536, ACT=6, ENS=5.
// v6: persistent kernel, v4-style GLOBAL partition (no island weight
// amplification), NO cache-maintenance ops. Inter-phase data crosses XCDs via
// relaxed AGENT-scope atomics (sc1 loads/stores, compiler-managed waitcnts);
// weights use normal cached loads and stay L2-resident across all 64 steps
// (L2 is never invalidated). Barrier = vmcnt drain + packed {gen|count} L3
// atomic. Eobs hoist (v4, verified). deter/dcat buffers eliminated.

#define B_ 256
#define T_ 64
#define ACT_ 6
#define EMBED_ 1536
#define OUTW_ 1216
#define NBLK 768
#define SCOPE_A __HIP_MEMORY_SCOPE_AGENT

typedef __attribute__((ext_vector_type(8))) short bf16x8;
typedef __attribute__((ext_vector_type(4))) float f32x4;
typedef unsigned long long u64;

__device__ inline unsigned short f2bf(float x) {
    union { float f; unsigned int u; } v; v.f = x;
    unsigned int r = v.u + 0x7fffu + ((v.u >> 16) & 1u);
    return (unsigned short)(r >> 16);
}
__device__ inline float bf2f(unsigned short h) {
    union { unsigned int u; float f; } v; v.u = ((unsigned int)h) << 16;
    return v.f;
}
__device__ inline float softplus_f(float x) { return x > 20.f ? x : log1pf(expf(x)); }
__device__ inline float sigmoid_f(float x) { return 1.f / (1.f + expf(-x)); }
__device__ inline float elu_f(float x) { return x > 0.f ? x : expm1f(x); }

// ---- agent-scope (device-coherent) access helpers: sc-bit loads/stores ----
union U16 { u64 u[2]; f32x4 f; bf16x8 h; };
__device__ inline u64 ald(const void* p) {
    return __hip_atomic_load((const u64*)p, __ATOMIC_RELAXED, SCOPE_A);
}
__device__ inline void ast(void* p, u64 v) {
    __hip_atomic_store((u64*)p, v, __ATOMIC_RELAXED, SCOPE_A);
}
__device__ inline f32x4 ald_f4(const float* p) {
    U16 r; const u64* q = (const u64*)p;
    r.u[0] = ald(q); r.u[1] = ald(q + 1); return r.f;
}
__device__ inline void ast_f4(float* p, f32x4 v) {
    U16 r; r.f = v; u64* q = (u64*)p;
    ast(q, r.u[0]); ast(q + 1, r.u[1]);
}
__device__ inline bf16x8 ald_h8(const unsigned short* p) {
    U16 r; const u64* q = (const u64*)p;
    r.u[0] = ald(q); r.u[1] = ald(q + 1); return r.h;
}
__device__ inline u64 pack4bf(f32x4 v) {
    return (u64)f2bf(v[0]) | ((u64)f2bf(v[1]) << 16)
         | ((u64)f2bf(v[2]) << 32) | ((u64)f2bf(v[3]) << 48);
}

// ---------------- flat fp32 -> bf16 convert --------------------------------
__global__ __launch_bounds__(256)
void k_convert(const float* __restrict__ src, unsigned short* __restrict__ dst, long n4) {
    for (long i = blockIdx.x * 256 + threadIdx.x; i < n4; i += (long)gridDim.x * 256) {
        f32x4 v = *(const f32x4*)(src + i * 4);
        unsigned short* d = dst + i * 4;
        d[0] = f2bf(v[0]); d[1] = f2bf(v[1]); d[2] = f2bf(v[2]); d[3] = f2bf(v[3]);
    }
}

// ---------------- transpose + fp32->bf16 convert: dst[n][k] = src[k][n] ----
__global__ __launch_bounds__(256)
void k_transpose_cvt(const float* __restrict__ src, unsigned short* __restrict__ dst,
                     int K, int N) {
    __shared__ float tile[32][33];
    size_t off = (size_t)blockIdx.z * K * N;
    src += off; dst += off;
    int n0 = blockIdx.x * 32, k0 = blockIdx.y * 32;
    int tx = threadIdx.x, ty = threadIdx.y;
    for (int i = ty; i < 32; i += 8) tile[i][tx] = src[(size_t)(k0 + i) * N + n0 + tx];
    __syncthreads();
    for (int i = ty; i < 32; i += 8) dst[(size_t)(n0 + i) * K + k0 + tx] = f2bf(tile[tx][i]);
}

// ---------------- MFMA tile, depth-2 prefetch, A via agent-scope loads -----
// A row-major [M,K] bf16 (inter-phase data -> sc loads); Bt row-major [N,K]
// bf16 (weights -> normal cached loads).
template<int MF, int NF, int KI>
__device__ inline void mfma_tileA(const unsigned short* __restrict__ A, int lda,
                                  const unsigned short* __restrict__ Bt, int ldb,
                                  int row0, int col0, f32x4 acc[MF][NF]) {
    int lane = threadIdx.x & 63;
    int lr = lane & 15, q = lane >> 4;
    const unsigned short* ap = A + (size_t)(row0 + lr) * lda + q * 8;
    const unsigned short* bp = Bt + (size_t)(col0 + lr) * ldb + q * 8;
    bf16x8 a0[MF], b0[NF], a1[MF], b1[NF], a2[MF], b2[NF];
    auto ld = [&](bf16x8 (&av)[MF], bf16x8 (&bv)[NF], int kk) {
#pragma unroll
        for (int i = 0; i < MF; i++) av[i] = ald_h8(ap + (size_t)i * 16 * lda + kk);
#pragma unroll
        for (int j = 0; j < NF; j++) bv[j] = *(const bf16x8*)(bp + (size_t)j * 16 * ldb + kk);
    };
    auto mm = [&](bf16x8 (&av)[MF], bf16x8 (&bv)[NF]) {
#pragma unroll
        for (int i = 0; i < MF; i++)
#pragma unroll
            for (int j = 0; j < NF; j++)
                acc[i][j] = __builtin_amdgcn_mfma_f32_16x16x32_bf16(av[i], bv[j], acc[i][j], 0, 0, 0);
    };
    ld(a0, b0, 0);
    if (KI > 1) ld(a1, b1, 32);
#pragma unroll
    for (int s = 0; s < KI; s++) {
        if (s + 2 < KI) {
            const int ml = (s + 2) % 3;
            if (ml == 0) ld(a0, b0, (s + 2) * 32);
            else if (ml == 1) ld(a1, b1, (s + 2) * 32);
            else ld(a2, b2, (s + 2) * 32);
        }
        const int mc = s % 3;
        if (mc == 0) mm(a0, b0);
        else if (mc == 1) mm(a1, b1);
        else mm(a2, b2);
    }
}

// ---------------- Eobs precompute: Eobs[bt][n] = embed_bf[bt] @ W_obs[1024:,:]
__global__ __launch_bounds__(256)
void k_eobs(const unsigned short* __restrict__ ebf, const unsigned short* __restrict__ Wt_obs,
            unsigned short* __restrict__ Eobs) {
    int wave = threadIdx.x >> 6, lane = threadIdx.x & 63;
    int row0 = blockIdx.y * 128 + wave * 32, col0 = blockIdx.x * 32;
    f32x4 acc[2][2];
#pragma unroll
    for (int i = 0; i < 2; i++)
#pragma unroll
        for (int j = 0; j < 2; j++) { f32x4 z = {0.f, 0.f, 0.f, 0.f}; acc[i][j] = z; }
    // normal loads both sides here (everything is pre-persistent-kernel)
    {
        int lr = lane & 15, q = lane >> 4;
        const unsigned short* ap = ebf + (size_t)(row0 + lr) * 1536 + q * 8;
        const unsigned short* bp = Wt_obs + 1024 + (size_t)(col0 + lr) * 2560 + q * 8;
        for (int k = 0; k < 1536; k += 32) {
            bf16x8 av[2], bv[2];
#pragma unroll
            for (int i = 0; i < 2; i++) av[i] = *(const bf16x8*)(ap + (size_t)i * 16 * 1536 + k);
#pragma unroll
            for (int j = 0; j < 2; j++) bv[j] = *(const bf16x8*)(bp + (size_t)j * 16 * 2560 + k);
#pragma unroll
            for (int i = 0; i < 2; i++)
#pragma unroll
                for (int j = 0; j < 2; j++)
                    acc[i][j] = __builtin_amdgcn_mfma_f32_16x16x32_bf16(av[i], bv[j], acc[i][j], 0, 0, 0);
        }
    }
    int lr = lane & 15, q = lane >> 4;
#pragma unroll
    for (int i = 0; i < 2; i++)
#pragma unroll
        for (int j = 0; j < 2; j++)
#pragma unroll
            for (int r = 0; r < 4; r++) {
                int row = row0 + i * 16 + q * 4 + r;
                int col = col0 + j * 16 + lr;
                Eobs[(size_t)row * 1024 + col] = f2bf(acc[i][j][r]);
            }
}

// ---------------- persistent-kernel parameters -----------------------------
struct RP {
    const float* action;
    const float* eps_post;
    const float* eps_prior;
    const unsigned char* is_first;
    const int* ens_idx;
    const float* b_gru;
    const float* ln_g;
    const float* ln_b;
    const float* W_inp;
    const float* b_inp;
    const float* b_obs;
    const float* b_ens;
    const float* Wod;
    const float* bod;
    const float* Wed;
    const float* bed;
    const unsigned short* Wt_gru;  // [3072][2048]
    const unsigned short* Wt_obs;  // [1024][2560]
    const unsigned short* Wt_ens;  // [5][1024][1024]
    const unsigned short* Eobs;    // [B*T][1024] bf16
    float* deter_m;     // [256][1024]  (agent-scope)
    float* Gp;          // [2][256][3072] (agent-scope)
    float* hbuf;        // [256][1024]  elu'd (agent-scope)
    float* xobuf;       // [256][1024]  elu'd (agent-scope)
    unsigned short* xcat;    // [256][2048] (agent-scope)
    unsigned short* dnew_bf; // [256][1024] (agent-scope)
    float* out;
    u64* bar;           // packed {gen:32 | count:32}, zeroed
};

// ---------------- device barrier: packed count|gen, no cache ops -----------
__device__ inline void gbar(u64* pack) {
    __syncthreads();   // compiler drains vmcnt before s_barrier
    if (threadIdx.x == 0) {
        asm volatile("s_waitcnt vmcnt(0)" ::: "memory");
        u64 prev = __hip_atomic_fetch_add(pack, 1ull, __ATOMIC_RELAXED, SCOPE_A);
        unsigned g = (unsigned)(prev >> 32);
        if ((unsigned)prev == NBLK - 1u) {
            __hip_atomic_fetch_add(pack, (1ull << 32) - (u64)NBLK, __ATOMIC_RELAXED, SCOPE_A);
        } else {
            int guard = 0;
            while ((unsigned)(__hip_atomic_load(pack, __ATOMIC_RELAXED, SCOPE_A) >> 32) == g) {
                __builtin_amdgcn_s_sleep(2);
                if (++guard > 2000000) break;   // failsafe: no hang
            }
        }
    }
    __syncthreads();
}

// ---------------- the persistent scan kernel -------------------------------
__global__ __launch_bounds__(256, 3)
void rssm_pers(RP P) {
    const int id = blockIdx.x;
    const int tid = threadIdx.x;
    const int wave = tid >> 6, lane = tid & 63;
    const int lr = lane & 15, q = lane >> 4;

    __shared__ float s_red[4][32][66];    // GEMM cross-wave reduce (+pad)
    __shared__ float s_h[1024], s_xo[1024];
    __shared__ float s_par[256], s_acc[128], s_stoch[32], s_am[8];
    __shared__ float g_r1[4], g_r2[4], g_ms[2];

    // ======== GRU GEMM: 48 col-tiles(64) x 8 rowgrps(32) x 2 Ksplit ========
    auto gru_phase = [&]() {
        int col0 = (id % 48) * 64;
        int rest = id / 48;                 // 0..15
        int row0 = (rest & 7) * 32, ks = rest >> 3;
        f32x4 acc[2][4];
#pragma unroll
        for (int i = 0; i < 2; i++)
#pragma unroll
            for (int j = 0; j < 4; j++) { f32x4 z = {0.f,0.f,0.f,0.f}; acc[i][j] = z; }
        // wave K-slice 256 within this ks half (total K 1024 per block)
        mfma_tileA<2, 4, 8>(P.xcat + ks * 1024 + wave * 256, 2048,
                            P.Wt_gru + ks * 1024 + wave * 256, 2048, row0, col0, acc);
#pragma unroll
        for (int i = 0; i < 2; i++)
#pragma unroll
            for (int j = 0; j < 4; j++)
#pragma unroll
                for (int r = 0; r < 4; r++)
                    s_red[wave][i * 16 + q * 4 + r][j * 16 + lr] = acc[i][j][r];
        __syncthreads();
        int rr = tid >> 3, cc = (tid & 7) * 8;
        f32x4 v0, v1;
#pragma unroll
        for (int u = 0; u < 4; u++) {
            v0[u] = s_red[0][rr][cc + u] + s_red[1][rr][cc + u]
                  + s_red[2][rr][cc + u] + s_red[3][rr][cc + u];
            v1[u] = s_red[0][rr][cc + 4 + u] + s_red[1][rr][cc + 4 + u]
                  + s_red[2][rr][cc + 4 + u] + s_red[3][rr][cc + 4 + u];
        }
        float* dst = P.Gp + (size_t)ks * (B_ * 3072) + (size_t)(row0 + rr) * 3072 + col0 + cc;
        ast_f4(dst, v0);
        ast_f4(dst + 4, v1);
        __syncthreads();
    };

    // ======== gates: LN + GRU update, 256 blocks, thread = 4 consecutive j =
    auto gates_phase = [&](int t) {
        if (id >= B_) return;
        int b = id, j4 = tid * 4;
        const float* G0 = P.Gp + (size_t)b * 3072;
        const float* G1 = P.Gp + (size_t)(B_ * 3072) + (size_t)b * 3072;
        f32x4 a0 = ald_f4(G0 + j4) + ald_f4(G1 + j4);
        f32x4 a1 = ald_f4(G0 + j4 + 1024) + ald_f4(G1 + j4 + 1024);
        f32x4 a2 = ald_f4(G0 + j4 + 2048) + ald_f4(G1 + j4 + 2048);
        a0 += *(const f32x4*)(P.b_gru + j4);
        a1 += *(const f32x4*)(P.b_gru + j4 + 1024);
        a2 += *(const f32x4*)(P.b_gru + j4 + 2048);
        float s1 = 0.f, s2 = 0.f;
#pragma unroll
        for (int r = 0; r < 4; r++) {
            s1 += a0[r] + a1[r] + a2[r];
            s2 += a0[r]*a0[r] + a1[r]*a1[r] + a2[r]*a2[r];
        }
#pragma unroll
        for (int o = 32; o > 0; o >>= 1) { s1 += __shfl_down(s1, o, 64); s2 += __shfl_down(s2, o, 64); }
        if ((tid & 63) == 0) { g_r1[wave] = s1; g_r2[wave] = s2; }
        __syncthreads();
        if (tid == 0) {
            float a = g_r1[0] + g_r1[1] + g_r1[2] + g_r1[3];
            float c = g_r2[0] + g_r2[1] + g_r2[2] + g_r2[3];
            float mean = a / 3072.f;
            float var = c / 3072.f - mean * mean;
            g_ms[0] = mean; g_ms[1] = rsqrtf(var + 1e-5f);
        }
        __syncthreads();
        float mean = g_ms[0], rstd = g_ms[1];
        f32x4 lg0 = *(const f32x4*)(P.ln_g + j4), lb0 = *(const f32x4*)(P.ln_b + j4);
        f32x4 lg1 = *(const f32x4*)(P.ln_g + j4 + 1024), lb1 = *(const f32x4*)(P.ln_b + j4 + 1024);
        f32x4 lg2 = *(const f32x4*)(P.ln_g + j4 + 2048), lb2 = *(const f32x4*)(P.ln_b + j4 + 2048);
        f32x4 dmp = ald_f4(P.deter_m + (size_t)b * 1024 + j4);
        f32x4 dn;
#pragma unroll
        for (int r = 0; r < 4; r++) {
            float n0 = (a0[r] - mean) * rstd * lg0[r] + lb0[r];
            float n1 = (a1[r] - mean) * rstd * lg1[r] + lb1[r];
            float n2 = (a2[r] - mean) * rstd * lg2[r] + lb2[r];
            float reset = sigmoid_f(n0);
            float cand = tanhf(reset * n1);
            float upd = sigmoid_f(n2 - 1.f);   // UPDATE_BIAS = -1
            dn[r] = upd * cand + (1.f - upd) * dmp[r];
        }
        ast(P.dnew_bf + (size_t)b * 1024 + j4, pack4bf(dn));
        *(f32x4*)(P.out + ((size_t)b * T_ + t) * OUTW_ + 192 + j4) = dn;   // host-read only
        int tn = t + 1;
        if (tn < T_) {
            float m = P.is_first[b * T_ + tn] ? 0.f : 1.f;
            f32x4 dm;
#pragma unroll
            for (int r = 0; r < 4; r++) dm[r] = dn[r] * m;
            ast_f4(P.deter_m + (size_t)b * 1024 + j4, dm);
            ast(P.xcat + (size_t)b * 2048 + 1024 + j4, pack4bf(dm));
        }
        __syncthreads();
    };

    // ======== heads: 2 heads x 16 col-tiles(64) x 8 rowgrps = 256 blocks ===
    auto heads_phase = [&](int t) {
        if (id >= 256) return;
        int jc = id & 31, rowgrp = id >> 5;
        int head = jc >> 4, col0 = (jc & 15) * 64, row0 = rowgrp * 32;
        int e = P.ens_idx[t];
        f32x4 acc[2][4];
#pragma unroll
        for (int i = 0; i < 2; i++)
#pragma unroll
            for (int j = 0; j < 4; j++) { f32x4 z = {0.f,0.f,0.f,0.f}; acc[i][j] = z; }
        if (head == 0)
            mfma_tileA<2, 4, 8>(P.dnew_bf + wave * 256, 1024,
                                P.Wt_ens + (size_t)e * 1024 * 1024 + wave * 256, 1024,
                                row0, col0, acc);
        else
            mfma_tileA<2, 4, 8>(P.dnew_bf + wave * 256, 1024,
                                P.Wt_obs + wave * 256, 2560, row0, col0, acc);
#pragma unroll
        for (int i = 0; i < 2; i++)
#pragma unroll
            for (int j = 0; j < 4; j++)
#pragma unroll
                for (int r = 0; r < 4; r++)
                    s_red[wave][i * 16 + q * 4 + r][j * 16 + lr] = acc[i][j][r];
        __syncthreads();
        int rr = tid >> 3, cc = (tid & 7) * 8;
        int grow = row0 + rr;
        float sum[8];
#pragma unroll
        for (int u = 0; u < 8; u++)
            sum[u] = s_red[0][rr][cc + u] + s_red[1][rr][cc + u]
                   + s_red[2][rr][cc + u] + s_red[3][rr][cc + u];
        f32x4 o0, o1;
        if (head == 0) {
            f32x4 bb0 = *(const f32x4*)(P.b_ens + (size_t)e * 1024 + col0 + cc);
            f32x4 bb1 = *(const f32x4*)(P.b_ens + (size_t)e * 1024 + col0 + cc + 4);
#pragma unroll
            for (int u = 0; u < 4; u++) { o0[u] = elu_f(sum[u] + bb0[u]); o1[u] = elu_f(sum[4+u] + bb1[u]); }
            float* dst = P.hbuf + (size_t)grow * 1024 + col0 + cc;
            ast_f4(dst, o0); ast_f4(dst + 4, o1);
        } else {
            f32x4 bb0 = *(const f32x4*)(P.b_obs + col0 + cc);
            f32x4 bb1 = *(const f32x4*)(P.b_obs + col0 + cc + 4);
            bf16x8 ev = *(const bf16x8*)(P.Eobs + ((size_t)grow * T_ + t) * 1024 + col0 + cc);
#pragma unroll
            for (int u = 0; u < 4; u++) {
                o0[u] = elu_f(sum[u] + bb0[u] + bf2f((unsigned short)ev[u]));
                o1[u] = elu_f(sum[4+u] + bb1[u] + bf2f((unsigned short)ev[4+u]));
            }
            float* dst = P.xobuf + (size_t)grow * 1024 + col0 + cc;
            ast_f4(dst, o0); ast_f4(dst + 4, o1);
        }
        __syncthreads();
    };

    // ======== dist + next-step stoch-half prep, 256 blocks ================
    auto dist_prep = [&](int t) {
        if (id >= B_) return;
        int b = id;
        if (t >= 0) {
            int e = P.ens_idx[t];
            {
                int i = tid * 4;
                f32x4 hv = ald_f4(P.hbuf + (size_t)b * 1024 + i);
                f32x4 xv = ald_f4(P.xobuf + (size_t)b * 1024 + i);
                *(f32x4*)(s_h + i) = hv;
                *(f32x4*)(s_xo + i) = xv;
            }
            __syncthreads();
            {   // dist matmuls: 128 output cols x 2 K-halves
                int kh = tid >> 7, c = tid & 127;
                int k0 = kh * 512;
                float acc = 0.f;
                if (c < 64) {
                    const float* W = P.Wed + (size_t)e * 65536 + c;
#pragma unroll 8
                    for (int k = 0; k < 512; k++) acc += s_h[k0 + k] * W[(size_t)(k0 + k) * 64];
                } else {
                    const float* W = P.Wod + (c - 64);
#pragma unroll 8
                    for (int k = 0; k < 512; k++) acc += s_xo[k0 + k] * W[(size_t)(k0 + k) * 64];
                }
                s_par[tid] = acc;
            }
            __syncthreads();
            if (tid < 128) {
                int c = tid & 63;
                float acc = s_par[tid] + s_par[tid + 128];
                acc += (tid < 64) ? P.bed[e * 64 + c] : P.bod[c];
                s_acc[tid] = acc;
            }
            __syncthreads();
            if (tid < 32) {
                float pm = s_acc[tid];
                float ps = softplus_f(s_acc[32 + tid]) + 0.1f;
                float om = s_acc[64 + tid];
                float os = softplus_f(s_acc[96 + tid]) + 0.1f;
                size_t bt = (size_t)b * T_ + t;
                float prior = pm + ps * P.eps_prior[bt * 32 + tid];
                float post = om + os * P.eps_post[bt * 32 + tid];
                float* o = P.out + bt * OUTW_;
                o[tid] = om; o[32 + tid] = os; o[64 + tid] = post;
                o[96 + tid] = pm; o[128 + tid] = ps; o[160 + tid] = prior;
                s_stoch[tid] = post;
            }
        } else {
            if (tid < 32) s_stoch[tid] = 0.f;
        }
        int tn = t + 1;
        if (tn < T_) {
            __syncthreads();
            float m = P.is_first[b * T_ + tn] ? 0.f : 1.f;
            if (tid < ACT_) s_am[tid] = P.action[((size_t)b * T_ + tn) * ACT_ + tid] * m;
            __syncthreads();
            int n4 = tid * 4;
            f32x4 sa = {0.f, 0.f, 0.f, 0.f};
#pragma unroll
            for (int k = 0; k < 32; k++) {
                f32x4 w = *(const f32x4*)(P.W_inp + k * 1024 + n4);
                float sv = s_stoch[k];
#pragma unroll
                for (int r = 0; r < 4; r++) sa[r] += sv * w[r];
            }
            f32x4 av = *(const f32x4*)(P.b_inp + n4);
#pragma unroll
            for (int r = 0; r < 4; r++) av[r] += m * sa[r];
#pragma unroll
            for (int k = 0; k < ACT_; k++) {
                f32x4 w = *(const f32x4*)(P.W_inp + (32 + k) * 1024 + n4);
                float amv = s_am[k];
#pragma unroll
                for (int r = 0; r < 4; r++) av[r] += amv * w[r];
            }
            f32x4 xo;
#pragma unroll
            for (int r = 0; r < 4; r++) xo[r] = elu_f(av[r]);
            ast(P.xcat + (size_t)b * 2048 + n4, pack4bf(xo));
            if (t < 0) {   // init carries for step 0
                f32x4 z = {0.f, 0.f, 0.f, 0.f};
                ast_f4(P.deter_m + (size_t)b * 1024 + n4, z);
                ast(P.xcat + (size_t)b * 2048 + 1024 + n4, 0ull);
            }
        }
        __syncthreads();
    };

    // ================= the scan =================
    dist_prep(-1);
    gbar(P.bar);
    for (int t = 0; t < T_; ++t) {
        gru_phase();
        gbar(P.bar);
        gates_phase(t);
        gbar(P.bar);
        heads_phase(t);
        gbar(P.bar);
        dist_prep(t);
        gbar(P.bar);
    }
}

extern "C" void kernel_launch(void* const* d_in, const int* in_sizes, int n_in,
                              void* d_out, int out_size, void* d_ws, size_t ws_size,
                              hipStream_t stream) {
    const float* embed      = (const float*)d_in[0];
    const float* action     = (const float*)d_in[1];
    const float* eps_post   = (const float*)d_in[2];
    const float* eps_prior  = (const float*)d_in[3];
    const unsigned char* is_first = (const unsigned char*)d_in[4];
    const int* ens_idx      = (const int*)d_in[5];
    const float* W_gru      = (const float*)d_in[6];
    const float* b_gru      = (const float*)d_in[7];
    const float* ln_g       = (const float*)d_in[8];
    const float* ln_b       = (const float*)d_in[9];
    const float* W_inp      = (const float*)d_in[10];
    const float* b_inp      = (const float*)d_in[11];
    const float* W_obs      = (const float*)d_in[12];
    const float* b_obs      = (const float*)d_in[13];
    const float* W_ens      = (const float*)d_in[14];
    const float* b_ens      = (const float*)d_in[15];
    const float* W_obs_dist = (const float*)d_in[16];
    const float* b_obs_dist = (const float*)d_in[17];
    const float* W_ens_dist = (const float*)d_in[18];
    const float* b_ens_dist = (const float*)d_in[19];
    float* out = (float*)d_out;

    char* p = (char*)d_ws;
    auto take = [&](size_t bytes) -> char* {
        char* r = p;
        p += (bytes + 255) & ~(size_t)255;
        return r;
    };
    unsigned short* Wt_gru = (unsigned short*)take((size_t)3072 * 2048 * 2);
    unsigned short* Wt_obs = (unsigned short*)take((size_t)1024 * 2560 * 2);
    unsigned short* Wt_ens = (unsigned short*)take((size_t)5 * 1024 * 1024 * 2);
    float* deter_m = (float*)take((size_t)B_ * 1024 * 4);
    float* Gp      = (float*)take((size_t)2 * B_ * 3072 * 4);
    float* hbuf    = (float*)take((size_t)B_ * 1024 * 4);
    float* xobuf   = (float*)take((size_t)B_ * 1024 * 4);
    unsigned short* xcat    = (unsigned short*)take((size_t)B_ * 2048 * 2);
    unsigned short* dnew_bf = (unsigned short*)take((size_t)B_ * 1024 * 2);
    unsigned short* ebf  = (unsigned short*)take((size_t)B_ * T_ * EMBED_ * 2);
    unsigned short* Eobs = (unsigned short*)take((size_t)B_ * T_ * 1024 * 2);
    u64* bar = (u64*)take(256);
    if ((size_t)(p - (char*)d_ws) > ws_size) return;

    hipMemsetAsync(bar, 0, 256, stream);

    // ---- one-off precompute (normal kernels; boundary flush publishes) ----
    k_transpose_cvt<<<dim3(96, 64, 1), dim3(32, 8), 0, stream>>>(W_gru, Wt_gru, 2048, 3072);
    k_transpose_cvt<<<dim3(32, 80, 1), dim3(32, 8), 0, stream>>>(W_obs, Wt_obs, 2560, 1024);
    k_transpose_cvt<<<dim3(32, 32, 5), dim3(32, 8), 0, stream>>>(W_ens, Wt_ens, 1024, 1024);
    k_convert<<<dim3(2048), dim3(256), 0, stream>>>(embed, ebf, (long)B_ * T_ * EMBED_ / 4);
    k_eobs<<<dim3(32, 128), dim3(256), 0, stream>>>(ebf, Wt_obs, Eobs);

    RP P;
    P.action = action; P.eps_post = eps_post; P.eps_prior = eps_prior;
    P.is_first = is_first; P.ens_idx = ens_idx;
    P.b_gru = b_gru; P.ln_g = ln_g; P.ln_b = ln_b;
    P.W_inp = W_inp; P.b_inp = b_inp; P.b_obs = b_obs; P.b_ens = b_ens;
    P.Wod = W_obs_dist; P.bod = b_obs_dist; P.Wed = W_ens_dist; P.bed = b_ens_dist;
    P.Wt_gru = Wt_gru; P.Wt_obs = Wt_obs; P.Wt_ens = Wt_ens; P.Eobs = Eobs;
    P.deter_m = deter_m; P.Gp = Gp; P.hbuf = hbuf; P.xobuf = xobuf;
    P.xcat = xcat; P.dnew_bf = dnew_bf; P.out = out; P.bar = bar;

    rssm_pers<<<dim3(NBLK), dim3(256), 0, stream>>>(P);
}